// Round 4
// baseline (169.517 us; speedup 1.0000x reference)
//
#include <hip/hip_runtime.h>

// HardNetLoss: a = x[:8192], p = x[8192:], d_ij = sqrt((1 - a_i·p_j + 1e-6)*2)
// pos_i = d_ii ; neg_i = min(min_{j!=i} d_ji, min_{j!=i} d_ij)
// out = mean(relu(1 - neg + pos))
//
// R4: barrier-free K-loop. No LDS staging: fragments are loaded straight
// from L2 (inputs are 8.4 MB bf16, L2-resident per-XCD with the block
// swizzle) as global_load_dwordx4, interleaved 1:1 with MFMA by the
// compiler's natural vmcnt pipelining (the AITER pattern the 2-barrier
// LDS loop cannot express). Only one __syncthreads left (epilogue
// transpose). Wave tile 64x128, block 128x256.

#define CNT   8192
#define KDIM  256
#define BIGF  3.0e38f

typedef __bf16 bf16x8 __attribute__((ext_vector_type(8)));
typedef float  f32x4  __attribute__((ext_vector_type(4)));

__device__ __forceinline__ unsigned short f2bf(float f) {
    unsigned u = __float_as_uint(f);
    u += 0x7FFFu + ((u >> 16) & 1u);          // round-to-nearest-even
    return (unsigned short)(u >> 16);
}

// ---------------- fast path ----------------

// x fp32 [16384][256] -> xb bf16 row-major (no swizzle). Inits min slots.
__global__ __launch_bounds__(256) void convert_init_kernel(
    const float* __restrict__ x, unsigned short* __restrict__ xb,
    unsigned* __restrict__ mins)
{
    int t = blockIdx.x * 256 + threadIdx.x;   // 524288 threads, 8 elems each
    int elem = t * 8;
    float4 v0 = *(const float4*)(x + elem);
    float4 v1 = *(const float4*)(x + elem + 4);
    uint4 w;
    w.x = (unsigned)f2bf(v0.x) | ((unsigned)f2bf(v0.y) << 16);
    w.y = (unsigned)f2bf(v0.z) | ((unsigned)f2bf(v0.w) << 16);
    w.z = (unsigned)f2bf(v1.x) | ((unsigned)f2bf(v1.y) << 16);
    w.w = (unsigned)f2bf(v1.z) | ((unsigned)f2bf(v1.w) << 16);
    *(uint4*)(xb + elem) = w;
    if (t < 2 * CNT) mins[t] = 0x7F7FFFFFu;   // FLT_MAX bits
}

// block tile 128(m) x 256(n); 4 waves 2x2; wave tile 64x128 of 16x16x32 MFMA.
#define TST 132                                // T leading stride (f32)
__global__ __launch_bounds__(256, 2) void dist4_kernel(
    const unsigned short* __restrict__ Ab, const unsigned short* __restrict__ Pb,
    unsigned* __restrict__ g_rowmin, unsigned* __restrict__ g_colmin,
    float* __restrict__ g_pos)
{
    __shared__ float T[32 * TST];             // 16.9 KB (epilogue transpose only)

    const int tid  = threadIdx.x;
    // XCD-aware swizzle: 8 regions of 16x16 blocks (1MB A + 2MB P per XCD L2)
    const int l    = blockIdx.x;
    const int xcd  = l & 7;
    const int i    = l >> 3;                  // 0..255
    const int bm   = (xcd >> 1) * 16 + (i & 15);   // 0..63
    const int bn   = (xcd & 1) * 16 + (i >> 4);    // 0..31

    const int wave = tid >> 6;
    const int lane = tid & 63;
    const int quad = lane >> 4;
    const int l15  = lane & 15;
    const int wm   = wave >> 1;               // 0..1 : m half
    const int wn   = wave & 1;                // 0..1 : n half

    f32x4 acc[4][8];
    #pragma unroll
    for (int a = 0; a < 4; a++)
        #pragma unroll
        for (int b = 0; b < 8; b++)
            acc[a][b] = (f32x4){0.f, 0.f, 0.f, 0.f};

    // fragment byte offsets into Ab/Pb (row-major, 512 B/row):
    // A row = bm*128 + wm*64 + mi*16 + l15 ; k-chunk base = quad*16 bytes
    const char* Abase = (const char*)Ab;
    const char* Pbase = (const char*)Pb;
    size_t a_off[4], b_off[8];
    #pragma unroll
    for (int mi = 0; mi < 4; mi++)
        a_off[mi] = ((size_t)(bm * 128 + wm * 64 + mi * 16 + l15) << 9) + quad * 16;
    #pragma unroll
    for (int ni = 0; ni < 8; ni++)
        b_off[ni] = ((size_t)(bn * 256 + wn * 128 + ni * 16 + l15) << 9) + quad * 16;

    // K-loop: 8 steps of K=32; 12 dwordx4 loads + 32 MFMA per step, no barriers.
    #pragma unroll
    for (int ks = 0; ks < 8; ks++) {
        bf16x8 af[4], bfr[8];
        #pragma unroll
        for (int mi = 0; mi < 4; mi++)
            af[mi] = *(const bf16x8*)(Abase + a_off[mi] + ks * 64);
        #pragma unroll
        for (int ni = 0; ni < 8; ni++)
            bfr[ni] = *(const bf16x8*)(Pbase + b_off[ni] + ks * 64);
        #pragma unroll
        for (int mi = 0; mi < 4; mi++)
            #pragma unroll
            for (int ni = 0; ni < 8; ni++)
                acc[mi][ni] = __builtin_amdgcn_mfma_f32_16x16x32_bf16(
                    af[mi], bfr[ni], acc[mi][ni], 0, 0, 0);
    }

    // ---- epilogue. C/D layout: col = lane&15, row = quad*4 + reg (verified).
    // local row rl = wm*64 + mi*16 + quad*4 + r (0..127)
    // local col cl = wn*128 + ni*16 + l15      (0..255)

    // diagonal blocks: global row bm*128+rl == col bn*256+cl  <=>  (bm>>1)==bn
    if ((bm >> 1) == bn) {
        const int dstart = (bm & 1) * 128;
        #pragma unroll
        for (int mi = 0; mi < 4; mi++)
            #pragma unroll
            for (int ni = 0; ni < 8; ni++)
                #pragma unroll
                for (int r = 0; r < 4; r++) {
                    int rl = wm * 64 + mi * 16 + quad * 4 + r;
                    int cl = wn * 128 + ni * 16 + l15;
                    if (cl == rl + dstart) {
                        g_pos[bm * 128 + rl] = (1.0f - acc[mi][ni][r] + 1e-6f) * 2.0f;
                        acc[mi][ni][r] = -BIGF;
                    }
                }
    }

    // col-direction (min over rows => max s over m): in-lane + 2 quad shuffles
    #pragma unroll
    for (int ni = 0; ni < 8; ni++) {
        float v = -BIGF;
        #pragma unroll
        for (int mi = 0; mi < 4; mi++)
            #pragma unroll
            for (int r = 0; r < 4; r++)
                v = fmaxf(v, acc[mi][ni][r]);
        v = fmaxf(v, __shfl_xor(v, 16, 64));
        v = fmaxf(v, __shfl_xor(v, 32, 64));
        if (quad == 0) {
            float tt = fmaxf((1.0f - v + 1e-6f) * 2.0f, 0.0f);
            atomicMin(&g_colmin[bn * 256 + wn * 128 + ni * 16 + l15],
                      __float_as_uint(tt));
        }
    }

    // row-direction: fold over ni in-lane, then LDS transpose (r contiguous)
    float rmax[4][4];
    #pragma unroll
    for (int mi = 0; mi < 4; mi++)
        #pragma unroll
        for (int r = 0; r < 4; r++) {
            float v = acc[mi][0][r];
            #pragma unroll
            for (int ni = 1; ni < 8; ni++) v = fmaxf(v, acc[mi][ni][r]);
            rmax[mi][r] = v;
        }
    const int centry = wn * 16 + l15;         // 0..31
    #pragma unroll
    for (int mi = 0; mi < 4; mi++) {
        f32x4 v = {rmax[mi][0], rmax[mi][1], rmax[mi][2], rmax[mi][3]};
        *(f32x4*)&T[centry * TST + wm * 64 + mi * 16 + quad * 4] = v;
    }
    __syncthreads();

    if (tid < 128) {
        int row = tid;
        float v0 = T[row], v1 = T[TST + row];
        #pragma unroll
        for (int c = 2; c < 32; c += 2) {
            v0 = fmaxf(v0, T[c * TST + row]);
            v1 = fmaxf(v1, T[(c + 1) * TST + row]);
        }
        float v = fmaxf(v0, v1);
        float tt = fmaxf((1.0f - v + 1e-6f) * 2.0f, 0.0f);
        atomicMin(&g_rowmin[bm * 128 + row], __float_as_uint(tt));
    }
}

__global__ __launch_bounds__(1024) void finalize_t_kernel(
    const unsigned* __restrict__ rm, const unsigned* __restrict__ cm,
    const float* __restrict__ post, float* __restrict__ out)
{
    float local = 0.f;
    for (int i = threadIdx.x; i < CNT; i += 1024) {
        float t   = fminf(__uint_as_float(rm[i]), __uint_as_float(cm[i]));
        float neg = sqrtf(fmaxf(t, 0.f));
        float pos = sqrtf(fmaxf(post[i], 0.f));
        local += fmaxf(1.0f - neg + pos, 0.0f);
    }
    #pragma unroll
    for (int m = 1; m < 64; m <<= 1) local += __shfl_xor(local, m, 64);
    __shared__ float wsum[16];
    if ((threadIdx.x & 63) == 0) wsum[threadIdx.x >> 6] = local;
    __syncthreads();
    if (threadIdx.x == 0) {
        float s = 0.f;
        #pragma unroll
        for (int w = 0; w < 16; w++) s += wsum[w];
        out[0] = s * (1.0f / (float)CNT);
    }
}

// ---------------- fallback path (round-1, known passing; 96 KB ws) ----------------

#define BM 128
#define BN 128
#define BK 64
#define KST (BK + 8)

__global__ __launch_bounds__(256) void init_min_kernel(unsigned* buf, int n) {
    int i = blockIdx.x * 256 + threadIdx.x;
    if (i < n) buf[i] = 0x7F7FFFFFu;
}

__global__ __launch_bounds__(256) void dist_tile_kernel(
    const float* __restrict__ A, const float* __restrict__ P,
    unsigned* __restrict__ g_rowmin, unsigned* __restrict__ g_colmin,
    float* __restrict__ g_pos)
{
    __shared__ unsigned short As[BM * KST];
    __shared__ unsigned short Bs[BN * KST];
    __shared__ unsigned redrow[BM];
    __shared__ unsigned redcol[BN];

    const int tid  = threadIdx.x;
    const int bm   = blockIdx.y;
    const int bn   = blockIdx.x;
    const int wave = tid >> 6;
    const int lane = tid & 63;
    const int quad = lane >> 4;
    const int l15  = lane & 15;
    const int m_off = (wave >> 1) * 64;
    const int n_off = (wave & 1) * 64;

    if (tid < BM) redrow[tid] = 0x7F7FFFFFu;
    if (tid < BN) redcol[tid] = 0x7F7FFFFFu;

    f32x4 acc[4][4];
    #pragma unroll
    for (int i = 0; i < 4; i++)
        #pragma unroll
        for (int j = 0; j < 4; j++)
            acc[i][j] = (f32x4){0.f, 0.f, 0.f, 0.f};

    const int srow = tid >> 4;
    const int scol = tid & 15;

    for (int kc = 0; kc < KDIM / BK; kc++) {
        #pragma unroll
        for (int i = 0; i < 8; i++) {
            int r = srow + i * 16;
            float4 va = *(const float4*)(A + (size_t)(bm * BM + r) * KDIM + kc * BK + scol * 4);
            float4 vb = *(const float4*)(P + (size_t)(bn * BN + r) * KDIM + kc * BK + scol * 4);
            ushort4 wa, wb;
            wa.x = f2bf(va.x); wa.y = f2bf(va.y); wa.z = f2bf(va.z); wa.w = f2bf(va.w);
            wb.x = f2bf(vb.x); wb.y = f2bf(vb.y); wb.z = f2bf(vb.z); wb.w = f2bf(vb.w);
            *(ushort4*)(&As[r * KST + scol * 4]) = wa;
            *(ushort4*)(&Bs[r * KST + scol * 4]) = wb;
        }
        __syncthreads();
        #pragma unroll
        for (int ks = 0; ks < BK / 32; ks++) {
            bf16x8 af[4], bfr[4];
            #pragma unroll
            for (int mi = 0; mi < 4; mi++)
                af[mi] = *(const bf16x8*)(&As[(m_off + mi * 16 + l15) * KST + ks * 32 + quad * 8]);
            #pragma unroll
            for (int ni = 0; ni < 4; ni++)
                bfr[ni] = *(const bf16x8*)(&Bs[(n_off + ni * 16 + l15) * KST + ks * 32 + quad * 8]);
            #pragma unroll
            for (int mi = 0; mi < 4; mi++)
                #pragma unroll
                for (int ni = 0; ni < 4; ni++)
                    acc[mi][ni] = __builtin_amdgcn_mfma_f32_16x16x32_bf16(
                        af[mi], bfr[ni], acc[mi][ni], 0, 0, 0);
        }
        __syncthreads();
    }

    float rmin[4][4], cmin[4];
    #pragma unroll
    for (int mi = 0; mi < 4; mi++)
        #pragma unroll
        for (int r = 0; r < 4; r++) rmin[mi][r] = BIGF;
    #pragma unroll
    for (int ni = 0; ni < 4; ni++) cmin[ni] = BIGF;

    const int grow0 = bm * BM + m_off + quad * 4;
    const int gcol0 = bn * BN + n_off + l15;

    #pragma unroll
    for (int mi = 0; mi < 4; mi++)
        #pragma unroll
        for (int ni = 0; ni < 4; ni++) {
            int gcol = gcol0 + ni * 16;
            #pragma unroll
            for (int r = 0; r < 4; r++) {
                int grow = grow0 + mi * 16 + r;
                float s = acc[mi][ni][r];
                float d = sqrtf((1.0f - s + 1e-6f) * 2.0f);
                float dm = d;
                if (grow == gcol) { g_pos[grow] = d; dm = BIGF; }
                rmin[mi][r] = fminf(rmin[mi][r], dm);
                cmin[ni]    = fminf(cmin[ni], dm);
            }
        }

    #pragma unroll
    for (int mi = 0; mi < 4; mi++)
        #pragma unroll
        for (int r = 0; r < 4; r++) {
            float v = rmin[mi][r];
            v = fminf(v, __shfl_xor(v, 1, 64));
            v = fminf(v, __shfl_xor(v, 2, 64));
            v = fminf(v, __shfl_xor(v, 4, 64));
            v = fminf(v, __shfl_xor(v, 8, 64));
            rmin[mi][r] = v;
        }
    #pragma unroll
    for (int ni = 0; ni < 4; ni++) {
        float v = cmin[ni];
        v = fminf(v, __shfl_xor(v, 16, 64));
        v = fminf(v, __shfl_xor(v, 32, 64));
        cmin[ni] = v;
    }

    if (l15 == 0) {
        #pragma unroll
        for (int mi = 0; mi < 4; mi++)
            #pragma unroll
            for (int r = 0; r < 4; r++)
                atomicMin(&redrow[m_off + mi * 16 + quad * 4 + r],
                          __float_as_uint(rmin[mi][r]));
    }
    if (quad == 0) {
        #pragma unroll
        for (int ni = 0; ni < 4; ni++)
            atomicMin(&redcol[n_off + ni * 16 + l15], __float_as_uint(cmin[ni]));
    }
    __syncthreads();

    if (tid < 128) atomicMin(&g_rowmin[bm * BM + tid], redrow[tid]);
    else           atomicMin(&g_colmin[bn * BN + (tid - 128)], redcol[tid - 128]);
}

__global__ __launch_bounds__(1024) void finalize_kernel(
    const unsigned* __restrict__ g_rowmin, const unsigned* __restrict__ g_colmin,
    const float* __restrict__ g_pos, float* __restrict__ out)
{
    float local = 0.f;
    for (int i = threadIdx.x; i < CNT; i += 1024) {
        float neg = fminf(__uint_as_float(g_rowmin[i]), __uint_as_float(g_colmin[i]));
        float v = 1.0f - neg + g_pos[i];
        local += fmaxf(v, 0.0f);
    }
    #pragma unroll
    for (int m = 1; m < 64; m <<= 1) local += __shfl_xor(local, m, 64);
    __shared__ float wsum[16];
    if ((threadIdx.x & 63) == 0) wsum[threadIdx.x >> 6] = local;
    __syncthreads();
    if (threadIdx.x == 0) {
        float s = 0.f;
        #pragma unroll
        for (int w = 0; w < 16; w++) s += wsum[w];
        out[0] = s * (1.0f / (float)CNT);
    }
}

// ---------------- host ----------------

extern "C" void kernel_launch(void* const* d_in, const int* in_sizes, int n_in,
                              void* d_out, int out_size, void* d_ws, size_t ws_size,
                              hipStream_t stream) {
    const float* x = (const float*)d_in[0];
    float* out = (float*)d_out;

    const size_t bf16_bytes = (size_t)2 * CNT * KDIM * 2;   // 8,388,608
    const size_t need = bf16_bytes + (size_t)2 * CNT * 4 + (size_t)CNT * 4;

    if (ws_size >= need) {
        unsigned short* xb   = (unsigned short*)d_ws;
        unsigned*       mins = (unsigned*)((char*)d_ws + bf16_bytes);
        float*          pos  = (float*)(mins + 2 * CNT);
        convert_init_kernel<<<dim3(2048), dim3(256), 0, stream>>>(x, xb, mins);
        dist4_kernel<<<dim3(2048), dim3(256), 0, stream>>>(
            xb, xb + (size_t)CNT * KDIM, mins, mins + CNT, pos);
        finalize_t_kernel<<<dim3(1), dim3(1024), 0, stream>>>(mins, mins + CNT, pos, out);
    } else {
        unsigned* rowmin = (unsigned*)d_ws;
        unsigned* colmin = rowmin + CNT;
        float*    pos    = (float*)(colmin + CNT);
        init_min_kernel<<<dim3(2 * CNT / 256), dim3(256), 0, stream>>>(rowmin, 2 * CNT);
        dist_tile_kernel<<<dim3(CNT / BN, CNT / BM), dim3(256), 0, stream>>>(
            x, x + (size_t)CNT * KDIM, rowmin, colmin, pos);
        finalize_kernel<<<dim3(1), dim3(1024), 0, stream>>>(rowmin, colmin, pos, out);
    }
}

// Round 5
// 115.528 us; speedup vs baseline: 1.4673x; 1.4673x over previous
//
#include <hip/hip_runtime.h>

// HardNetLoss: a = x[:8192], p = x[8192:], d_ij = sqrt((1 - a_i·p_j + 1e-6)*2)
// pos_i = d_ii ; neg_i = min(min_{j!=i} d_ji, min_{j!=i} d_ij)
// out = mean(relu(1 - neg + pos))
//
// R5: barrier-free K-loop with FRAGMENT-PACKED inputs. R4 failed because
// row-major fragment loads scatter into 16 transactions; now xb is packed so
// each MFMA fragment is a contiguous 1KB block (lane*16B) -> one coalesced
// global_load_dwordx4 per fragment. No LDS in the K-loop, no barriers;
// compiler pipelines loads vs MFMA with fine-grained vmcnt.
// Packed chunk index for row r, col c: ((r/16)*8 + c/32)*64 + ((c>>3)&3)*16 + (r&15).

#define CNT   8192
#define KDIM  256
#define BIGF  3.0e38f

typedef __bf16 bf16x8 __attribute__((ext_vector_type(8)));
typedef float  f32x4  __attribute__((ext_vector_type(4)));

__device__ __forceinline__ unsigned short f2bf(float f) {
    unsigned u = __float_as_uint(f);
    u += 0x7FFFu + ((u >> 16) & 1u);          // round-to-nearest-even
    return (unsigned short)(u >> 16);
}

// ---------------- fast path ----------------

// x fp32 [16384][256] -> xb bf16 fragment-packed. Also inits min slots.
__global__ __launch_bounds__(256) void convert_pack_kernel(
    const float* __restrict__ x, unsigned short* __restrict__ xb,
    unsigned* __restrict__ mins)
{
    int t = blockIdx.x * 256 + threadIdx.x;   // 524288 threads, 8 elems each
    int elem = t * 8;
    int row  = t >> 5;                        // elem >> 8
    int col  = (t & 31) * 8;
    float4 v0 = *(const float4*)(x + elem);
    float4 v1 = *(const float4*)(x + elem + 4);
    uint4 w;
    w.x = (unsigned)f2bf(v0.x) | ((unsigned)f2bf(v0.y) << 16);
    w.y = (unsigned)f2bf(v0.z) | ((unsigned)f2bf(v0.w) << 16);
    w.z = (unsigned)f2bf(v1.x) | ((unsigned)f2bf(v1.y) << 16);
    w.w = (unsigned)f2bf(v1.z) | ((unsigned)f2bf(v1.w) << 16);
    int chunk = (((row >> 4) * 8 + (col >> 5)) * 64) + (((col >> 3) & 3) * 16) + (row & 15);
    *(uint4*)(xb + chunk * 8) = w;
    if (t < 2 * CNT) mins[t] = 0x7F7FFFFFu;   // FLT_MAX bits
}

// block tile 128(m) x 256(n); 4 waves 2x2; wave tile 64x128 of 16x16x32 MFMA.
#define TST 132                                // T leading stride (f32)
__global__ __launch_bounds__(256, 2) void dist5_kernel(
    const unsigned short* __restrict__ Ab, const unsigned short* __restrict__ Pb,
    unsigned* __restrict__ g_rowmin, unsigned* __restrict__ g_colmin,
    float* __restrict__ g_pos)
{
    __shared__ float T[32 * TST];             // 16.9 KB (epilogue transpose only)

    const int tid  = threadIdx.x;
    // XCD-aware swizzle: 8 regions of 16x16 blocks (1MB A + 2MB P per XCD L2)
    const int l    = blockIdx.x;
    const int xcd  = l & 7;
    const int i    = l >> 3;                  // 0..255
    const int bm   = (xcd >> 1) * 16 + (i & 15);   // 0..63
    const int bn   = (xcd & 1) * 16 + (i >> 4);    // 0..31

    const int wave = tid >> 6;
    const int lane = tid & 63;
    const int quad = lane >> 4;
    const int l15  = lane & 15;
    const int wm   = wave >> 1;               // 0..1 : m half
    const int wn   = wave & 1;                // 0..1 : n half

    f32x4 acc[4][8];
    #pragma unroll
    for (int a = 0; a < 4; a++)
        #pragma unroll
        for (int b = 0; b < 8; b++)
            acc[a][b] = (f32x4){0.f, 0.f, 0.f, 0.f};

    // fragment base byte offsets: fragment (rg, ks) at ((rg*8+ks)*1024 + lane*16)
    const char* Abase = (const char*)Ab + lane * 16;
    const char* Pbase = (const char*)Pb + lane * 16;
    size_t a_off[4], b_off[8];
    #pragma unroll
    for (int mi = 0; mi < 4; mi++)
        a_off[mi] = ((size_t)(bm * 8 + wm * 4 + mi) << 13);    // rg * 8 * 1024
    #pragma unroll
    for (int ni = 0; ni < 8; ni++)
        b_off[ni] = ((size_t)(bn * 16 + wn * 8 + ni) << 13);

    // K-loop: 8 steps of K=32; 12 coalesced dwordx4 + 32 MFMA per step, no barriers.
    #pragma unroll
    for (int ks = 0; ks < 8; ks++) {
        bf16x8 af[4], bfr[8];
        #pragma unroll
        for (int mi = 0; mi < 4; mi++)
            af[mi] = *(const bf16x8*)(Abase + a_off[mi] + ks * 1024);
        #pragma unroll
        for (int ni = 0; ni < 8; ni++)
            bfr[ni] = *(const bf16x8*)(Pbase + b_off[ni] + ks * 1024);
        #pragma unroll
        for (int mi = 0; mi < 4; mi++)
            #pragma unroll
            for (int ni = 0; ni < 8; ni++)
                acc[mi][ni] = __builtin_amdgcn_mfma_f32_16x16x32_bf16(
                    af[mi], bfr[ni], acc[mi][ni], 0, 0, 0);
    }

    // ---- epilogue. C/D layout: col = lane&15, row = quad*4 + reg (verified).
    // local row rl = wm*64 + mi*16 + quad*4 + r (0..127)
    // local col cl = wn*128 + ni*16 + l15      (0..255)

    // diagonal blocks: global row bm*128+rl == col bn*256+cl  <=>  (bm>>1)==bn
    if ((bm >> 1) == bn) {
        const int dstart = (bm & 1) * 128;
        #pragma unroll
        for (int mi = 0; mi < 4; mi++)
            #pragma unroll
            for (int ni = 0; ni < 8; ni++)
                #pragma unroll
                for (int r = 0; r < 4; r++) {
                    int rl = wm * 64 + mi * 16 + quad * 4 + r;
                    int cl = wn * 128 + ni * 16 + l15;
                    if (cl == rl + dstart) {
                        g_pos[bm * 128 + rl] = (1.0f - acc[mi][ni][r] + 1e-6f) * 2.0f;
                        acc[mi][ni][r] = -BIGF;
                    }
                }
    }

    // col-direction (min over rows => max s over m): in-lane + 2 quad shuffles
    #pragma unroll
    for (int ni = 0; ni < 8; ni++) {
        float v = -BIGF;
        #pragma unroll
        for (int mi = 0; mi < 4; mi++)
            #pragma unroll
            for (int r = 0; r < 4; r++)
                v = fmaxf(v, acc[mi][ni][r]);
        v = fmaxf(v, __shfl_xor(v, 16, 64));
        v = fmaxf(v, __shfl_xor(v, 32, 64));
        if (quad == 0) {
            float tt = fmaxf((1.0f - v + 1e-6f) * 2.0f, 0.0f);
            atomicMin(&g_colmin[bn * 256 + wn * 128 + ni * 16 + l15],
                      __float_as_uint(tt));
        }
    }

    // row-direction: fold over ni in-lane, then LDS transpose (r contiguous)
    float rmax[4][4];
    #pragma unroll
    for (int mi = 0; mi < 4; mi++)
        #pragma unroll
        for (int r = 0; r < 4; r++) {
            float v = acc[mi][0][r];
            #pragma unroll
            for (int ni = 1; ni < 8; ni++) v = fmaxf(v, acc[mi][ni][r]);
            rmax[mi][r] = v;
        }
    const int centry = wn * 16 + l15;         // 0..31
    #pragma unroll
    for (int mi = 0; mi < 4; mi++) {
        f32x4 v = {rmax[mi][0], rmax[mi][1], rmax[mi][2], rmax[mi][3]};
        *(f32x4*)&T[centry * TST + wm * 64 + mi * 16 + quad * 4] = v;
    }
    __syncthreads();

    if (tid < 128) {
        int row = tid;
        float v0 = T[row], v1 = T[TST + row];
        #pragma unroll
        for (int c = 2; c < 32; c += 2) {
            v0 = fmaxf(v0, T[c * TST + row]);
            v1 = fmaxf(v1, T[(c + 1) * TST + row]);
        }
        float v = fmaxf(v0, v1);
        float tt = fmaxf((1.0f - v + 1e-6f) * 2.0f, 0.0f);
        atomicMin(&g_rowmin[bm * 128 + row], __float_as_uint(tt));
    }
}

__global__ __launch_bounds__(1024) void finalize_t_kernel(
    const unsigned* __restrict__ rm, const unsigned* __restrict__ cm,
    const float* __restrict__ post, float* __restrict__ out)
{
    float local = 0.f;
    for (int i = threadIdx.x; i < CNT; i += 1024) {
        float t   = fminf(__uint_as_float(rm[i]), __uint_as_float(cm[i]));
        float neg = sqrtf(fmaxf(t, 0.f));
        float pos = sqrtf(fmaxf(post[i], 0.f));
        local += fmaxf(1.0f - neg + pos, 0.0f);
    }
    #pragma unroll
    for (int m = 1; m < 64; m <<= 1) local += __shfl_xor(local, m, 64);
    __shared__ float wsum[16];
    if ((threadIdx.x & 63) == 0) wsum[threadIdx.x >> 6] = local;
    __syncthreads();
    if (threadIdx.x == 0) {
        float s = 0.f;
        #pragma unroll
        for (int w = 0; w < 16; w++) s += wsum[w];
        out[0] = s * (1.0f / (float)CNT);
    }
}

// ---------------- fallback path (round-1, known passing; 96 KB ws) ----------------

#define BM 128
#define BN 128
#define BK 64
#define KST (BK + 8)

__global__ __launch_bounds__(256) void init_min_kernel(unsigned* buf, int n) {
    int i = blockIdx.x * 256 + threadIdx.x;
    if (i < n) buf[i] = 0x7F7FFFFFu;
}

__global__ __launch_bounds__(256) void dist_tile_kernel(
    const float* __restrict__ A, const float* __restrict__ P,
    unsigned* __restrict__ g_rowmin, unsigned* __restrict__ g_colmin,
    float* __restrict__ g_pos)
{
    __shared__ unsigned short As[BM * KST];
    __shared__ unsigned short Bs[BN * KST];
    __shared__ unsigned redrow[BM];
    __shared__ unsigned redcol[BN];

    const int tid  = threadIdx.x;
    const int bm   = blockIdx.y;
    const int bn   = blockIdx.x;
    const int wave = tid >> 6;
    const int lane = tid & 63;
    const int quad = lane >> 4;
    const int l15  = lane & 15;
    const int m_off = (wave >> 1) * 64;
    const int n_off = (wave & 1) * 64;

    if (tid < BM) redrow[tid] = 0x7F7FFFFFu;
    if (tid < BN) redcol[tid] = 0x7F7FFFFFu;

    f32x4 acc[4][4];
    #pragma unroll
    for (int i = 0; i < 4; i++)
        #pragma unroll
        for (int j = 0; j < 4; j++)
            acc[i][j] = (f32x4){0.f, 0.f, 0.f, 0.f};

    const int srow = tid >> 4;
    const int scol = tid & 15;

    for (int kc = 0; kc < KDIM / BK; kc++) {
        #pragma unroll
        for (int i = 0; i < 8; i++) {
            int r = srow + i * 16;
            float4 va = *(const float4*)(A + (size_t)(bm * BM + r) * KDIM + kc * BK + scol * 4);
            float4 vb = *(const float4*)(P + (size_t)(bn * BN + r) * KDIM + kc * BK + scol * 4);
            ushort4 wa, wb;
            wa.x = f2bf(va.x); wa.y = f2bf(va.y); wa.z = f2bf(va.z); wa.w = f2bf(va.w);
            wb.x = f2bf(vb.x); wb.y = f2bf(vb.y); wb.z = f2bf(vb.z); wb.w = f2bf(vb.w);
            *(ushort4*)(&As[r * KST + scol * 4]) = wa;
            *(ushort4*)(&Bs[r * KST + scol * 4]) = wb;
        }
        __syncthreads();
        #pragma unroll
        for (int ks = 0; ks < BK / 32; ks++) {
            bf16x8 af[4], bfr[4];
            #pragma unroll
            for (int mi = 0; mi < 4; mi++)
                af[mi] = *(const bf16x8*)(&As[(m_off + mi * 16 + l15) * KST + ks * 32 + quad * 8]);
            #pragma unroll
            for (int ni = 0; ni < 4; ni++)
                bfr[ni] = *(const bf16x8*)(&Bs[(n_off + ni * 16 + l15) * KST + ks * 32 + quad * 8]);
            #pragma unroll
            for (int mi = 0; mi < 4; mi++)
                #pragma unroll
                for (int ni = 0; ni < 4; ni++)
                    acc[mi][ni] = __builtin_amdgcn_mfma_f32_16x16x32_bf16(
                        af[mi], bfr[ni], acc[mi][ni], 0, 0, 0);
        }
        __syncthreads();
    }

    float rmin[4][4], cmin[4];
    #pragma unroll
    for (int mi = 0; mi < 4; mi++)
        #pragma unroll
        for (int r = 0; r < 4; r++) rmin[mi][r] = BIGF;
    #pragma unroll
    for (int ni = 0; ni < 4; ni++) cmin[ni] = BIGF;

    const int grow0 = bm * BM + m_off + quad * 4;
    const int gcol0 = bn * BN + n_off + l15;

    #pragma unroll
    for (int mi = 0; mi < 4; mi++)
        #pragma unroll
        for (int ni = 0; ni < 4; ni++) {
            int gcol = gcol0 + ni * 16;
            #pragma unroll
            for (int r = 0; r < 4; r++) {
                int grow = grow0 + mi * 16 + r;
                float s = acc[mi][ni][r];
                float d = sqrtf((1.0f - s + 1e-6f) * 2.0f);
                float dm = d;
                if (grow == gcol) { g_pos[grow] = d; dm = BIGF; }
                rmin[mi][r] = fminf(rmin[mi][r], dm);
                cmin[ni]    = fminf(cmin[ni], dm);
            }
        }

    #pragma unroll
    for (int mi = 0; mi < 4; mi++)
        #pragma unroll
        for (int r = 0; r < 4; r++) {
            float v = rmin[mi][r];
            v = fminf(v, __shfl_xor(v, 1, 64));
            v = fminf(v, __shfl_xor(v, 2, 64));
            v = fminf(v, __shfl_xor(v, 4, 64));
            v = fminf(v, __shfl_xor(v, 8, 64));
            rmin[mi][r] = v;
        }
    #pragma unroll
    for (int ni = 0; ni < 4; ni++) {
        float v = cmin[ni];
        v = fminf(v, __shfl_xor(v, 16, 64));
        v = fminf(v, __shfl_xor(v, 32, 64));
        cmin[ni] = v;
    }

    if (l15 == 0) {
        #pragma unroll
        for (int mi = 0; mi < 4; mi++)
            #pragma unroll
            for (int r = 0; r < 4; r++)
                atomicMin(&redrow[m_off + mi * 16 + quad * 4 + r],
                          __float_as_uint(rmin[mi][r]));
    }
    if (quad == 0) {
        #pragma unroll
        for (int ni = 0; ni < 4; ni++)
            atomicMin(&redcol[n_off + ni * 16 + l15], __float_as_uint(cmin[ni]));
    }
    __syncthreads();

    if (tid < 128) atomicMin(&g_rowmin[bm * BM + tid], redrow[tid]);
    else           atomicMin(&g_colmin[bn * BN + (tid - 128)], redcol[tid - 128]);
}

__global__ __launch_bounds__(1024) void finalize_kernel(
    const unsigned* __restrict__ g_rowmin, const unsigned* __restrict__ g_colmin,
    const float* __restrict__ g_pos, float* __restrict__ out)
{
    float local = 0.f;
    for (int i = threadIdx.x; i < CNT; i += 1024) {
        float neg = fminf(__uint_as_float(g_rowmin[i]), __uint_as_float(g_colmin[i]));
        float v = 1.0f - neg + g_pos[i];
        local += fmaxf(v, 0.0f);
    }
    #pragma unroll
    for (int m = 1; m < 64; m <<= 1) local += __shfl_xor(local, m, 64);
    __shared__ float wsum[16];
    if ((threadIdx.x & 63) == 0) wsum[threadIdx.x >> 6] = local;
    __syncthreads();
    if (threadIdx.x == 0) {
        float s = 0.f;
        #pragma unroll
        for (int w = 0; w < 16; w++) s += wsum[w];
        out[0] = s * (1.0f / (float)CNT);
    }
}

// ---------------- host ----------------

extern "C" void kernel_launch(void* const* d_in, const int* in_sizes, int n_in,
                              void* d_out, int out_size, void* d_ws, size_t ws_size,
                              hipStream_t stream) {
    const float* x = (const float*)d_in[0];
    float* out = (float*)d_out;

    const size_t bf16_bytes = (size_t)2 * CNT * KDIM * 2;   // 8,388,608
    const size_t need = bf16_bytes + (size_t)2 * CNT * 4 + (size_t)CNT * 4;

    if (ws_size >= need) {
        unsigned short* xb   = (unsigned short*)d_ws;
        unsigned*       mins = (unsigned*)((char*)d_ws + bf16_bytes);
        float*          pos  = (float*)(mins + 2 * CNT);
        convert_pack_kernel<<<dim3(2048), dim3(256), 0, stream>>>(x, xb, mins);
        dist5_kernel<<<dim3(2048), dim3(256), 0, stream>>>(
            xb, xb + (size_t)CNT * KDIM, mins, mins + CNT, pos);
        finalize_t_kernel<<<dim3(1), dim3(1024), 0, stream>>>(mins, mins + CNT, pos, out);
    } else {
        unsigned* rowmin = (unsigned*)d_ws;
        unsigned* colmin = rowmin + CNT;
        float*    pos    = (float*)(colmin + CNT);
        init_min_kernel<<<dim3(2 * CNT / 256), dim3(256), 0, stream>>>(rowmin, 2 * CNT);
        dist_tile_kernel<<<dim3(CNT / BN, CNT / BM), dim3(256), 0, stream>>>(
            x, x + (size_t)CNT * KDIM, rowmin, colmin, pos);
        finalize_kernel<<<dim3(1), dim3(1024), 0, stream>>>(rowmin, colmin, pos, out);
    }
}

// Round 6
// 102.351 us; speedup vs baseline: 1.6562x; 1.1287x over previous
//
#include <hip/hip_runtime.h>
#include <hip/hip_fp8.h>

// HardNetLoss: a = x[:8192], p = x[8192:], d_ij = sqrt((1 - a_i·p_j + 1e-6)*2)
// pos_i = d_ii ; neg_i = min(min_{j!=i} d_ji, min_{j!=i} d_ij)
// out = mean(relu(1 - neg + pos))
//
// R6: fp8 e4m3 MFMA (non-scaled 16x16x32_fp8_fp8 = bf16 rate, HALF the feed
// bytes). Inputs pre-converted once to fragment-packed fp8: chunk (rg,ks2)
// holds two K=32 fragments (16B/lane, coalesced dwordx4). Barrier-free
// direct-from-L2 K-loop (R5 structure), XCD swizzle for L2 locality.
// Accuracy: elements ~N(0,1/256) => dot err sigma ~2e-3, loss err ~1e-3
// vs threshold 2.375e-2.
// Packed addr for (row,col): rg=row/16, m=row%16, ks=col/32, quad=(col%32)/8,
// j=col%8 -> ((rg*4+ks/2)*64 + quad*16 + m)*16 + (ks&1)*8 + j.

#define CNT   8192
#define KDIM  256
#define BIGF  3.0e38f

typedef float f32x4 __attribute__((ext_vector_type(4)));

__device__ __forceinline__ unsigned short f2bf(float f) {
    unsigned u = __float_as_uint(f);
    u += 0x7FFFu + ((u >> 16) & 1u);          // round-to-nearest-even
    return (unsigned short)(u >> 16);
}

__device__ __forceinline__ unsigned cvt4_fp8(float a, float b, float c, float d) {
#if __has_builtin(__builtin_amdgcn_cvt_pk_fp8_f32)
    unsigned v = __builtin_amdgcn_cvt_pk_fp8_f32(a, b, 0, false);
    v = __builtin_amdgcn_cvt_pk_fp8_f32(c, d, v, true);
    return v;
#else
    return (unsigned)__hip_fp8_e4m3(a).__x |
           ((unsigned)__hip_fp8_e4m3(b).__x << 8) |
           ((unsigned)__hip_fp8_e4m3(c).__x << 16) |
           ((unsigned)__hip_fp8_e4m3(d).__x << 24);
#endif
}

__device__ __forceinline__ long mk64(unsigned lo, unsigned hi) {
    return (long)(((unsigned long long)hi << 32) | (unsigned long long)lo);
}

// ---------------- fast path ----------------

// x fp32 [16384][256] -> xb fp8 fragment-pair-packed. Also inits min slots.
// Thread T -> chunk T: lane=T&63, ks2=(T>>6)&3, rg=T>>8; writes 16B.
__global__ __launch_bounds__(256) void convert8_kernel(
    const float* __restrict__ x, unsigned char* __restrict__ xb,
    unsigned* __restrict__ mins)
{
    int T    = blockIdx.x * 256 + threadIdx.x;   // 262144 threads
    int lane = T & 63;
    int ks2  = (T >> 6) & 3;
    int rg   = T >> 8;
    int quad = lane >> 4;
    int m    = lane & 15;
    int row  = rg * 16 + m;
    const float* src = x + (size_t)row * 256 + ks2 * 64 + quad * 8;
    float4 u0 = *(const float4*)(src);
    float4 u1 = *(const float4*)(src + 4);
    float4 u2 = *(const float4*)(src + 32);       // second K=32 half
    float4 u3 = *(const float4*)(src + 36);
    uint4 w;
    w.x = cvt4_fp8(u0.x, u0.y, u0.z, u0.w);       // ks even, j 0..3
    w.y = cvt4_fp8(u1.x, u1.y, u1.z, u1.w);       // ks even, j 4..7
    w.z = cvt4_fp8(u2.x, u2.y, u2.z, u2.w);       // ks odd,  j 0..3
    w.w = cvt4_fp8(u3.x, u3.y, u3.z, u3.w);       // ks odd,  j 4..7
    *(uint4*)(xb + (size_t)T * 16) = w;
    if (T < 2 * CNT) mins[T] = 0x7F7FFFFFu;       // FLT_MAX bits
}

// block tile 128(m) x 256(n); 4 waves 2x2; wave tile 64x128 of 16x16x32 MFMA.
#define TST 132                                // T leading stride (f32)
__global__ __launch_bounds__(256, 2) void dist6_kernel(
    const unsigned char* __restrict__ Ab, const unsigned char* __restrict__ Pb,
    unsigned* __restrict__ g_rowmin, unsigned* __restrict__ g_colmin,
    float* __restrict__ g_pos)
{
    __shared__ float T[32 * TST];             // 16.9 KB (epilogue transpose only)

    const int tid  = threadIdx.x;
    // XCD-aware swizzle: 8 regions of 16x16 blocks
    const int l    = blockIdx.x;
    const int xcd  = l & 7;
    const int i    = l >> 3;                  // 0..255
    const int bm   = (xcd >> 1) * 16 + (i & 15);   // 0..63
    const int bn   = (xcd & 1) * 16 + (i >> 4);    // 0..31

    const int wave = tid >> 6;
    const int lane = tid & 63;
    const int quad = lane >> 4;
    const int l15  = lane & 15;
    const int wm   = wave >> 1;               // 0..1 : m half
    const int wn   = wave & 1;                // 0..1 : n half

    f32x4 acc[4][8];
    #pragma unroll
    for (int a = 0; a < 4; a++)
        #pragma unroll
        for (int b = 0; b < 8; b++)
            acc[a][b] = (f32x4){0.f, 0.f, 0.f, 0.f};

    // chunk (rg, ks2) = 1 KB at (rg*4 + ks2)*1024; lane slot +lane*16
    const char* Abase = (const char*)Ab + lane * 16;
    const char* Pbase = (const char*)Pb + lane * 16;
    size_t a_off[4], b_off[8];
    #pragma unroll
    for (int mi = 0; mi < 4; mi++)
        a_off[mi] = ((size_t)(bm * 8 + wm * 4 + mi) << 12);   // rg * 4 * 1024
    #pragma unroll
    for (int ni = 0; ni < 8; ni++)
        b_off[ni] = ((size_t)(bn * 16 + wn * 8 + ni) << 12);

    // K-loop: 4 ks2 steps; 12 coalesced dwordx4 + 64 MFMA per step, no barriers.
    #pragma unroll
    for (int ks2 = 0; ks2 < 4; ks2++) {
        uint4 a4[4], b4[8];
        #pragma unroll
        for (int mi = 0; mi < 4; mi++)
            a4[mi] = *(const uint4*)(Abase + a_off[mi] + ks2 * 1024);
        #pragma unroll
        for (int ni = 0; ni < 8; ni++)
            b4[ni] = *(const uint4*)(Pbase + b_off[ni] + ks2 * 1024);
        #pragma unroll
        for (int h = 0; h < 2; h++) {
            long af[4], bf[8];
            #pragma unroll
            for (int mi = 0; mi < 4; mi++)
                af[mi] = h ? mk64(a4[mi].z, a4[mi].w) : mk64(a4[mi].x, a4[mi].y);
            #pragma unroll
            for (int ni = 0; ni < 8; ni++)
                bf[ni] = h ? mk64(b4[ni].z, b4[ni].w) : mk64(b4[ni].x, b4[ni].y);
            #pragma unroll
            for (int mi = 0; mi < 4; mi++)
                #pragma unroll
                for (int ni = 0; ni < 8; ni++)
                    acc[mi][ni] = __builtin_amdgcn_mfma_f32_16x16x32_fp8_fp8(
                        af[mi], bf[ni], acc[mi][ni], 0, 0, 0);
        }
    }

    // ---- epilogue. C/D layout: col = lane&15, row = quad*4 + reg (verified).
    // local row rl = wm*64 + mi*16 + quad*4 + r (0..127)
    // local col cl = wn*128 + ni*16 + l15      (0..255)

    if ((bm >> 1) == bn) {                    // diagonal band
        const int dstart = (bm & 1) * 128;
        #pragma unroll
        for (int mi = 0; mi < 4; mi++)
            #pragma unroll
            for (int ni = 0; ni < 8; ni++)
                #pragma unroll
                for (int r = 0; r < 4; r++) {
                    int rl = wm * 64 + mi * 16 + quad * 4 + r;
                    int cl = wn * 128 + ni * 16 + l15;
                    if (cl == rl + dstart) {
                        g_pos[bm * 128 + rl] = (1.0f - acc[mi][ni][r] + 1e-6f) * 2.0f;
                        acc[mi][ni][r] = -BIGF;
                    }
                }
    }

    // col-direction (min over rows => max s over m): in-lane + 2 quad shuffles
    #pragma unroll
    for (int ni = 0; ni < 8; ni++) {
        float v = -BIGF;
        #pragma unroll
        for (int mi = 0; mi < 4; mi++)
            #pragma unroll
            for (int r = 0; r < 4; r++)
                v = fmaxf(v, acc[mi][ni][r]);
        v = fmaxf(v, __shfl_xor(v, 16, 64));
        v = fmaxf(v, __shfl_xor(v, 32, 64));
        if (quad == 0) {
            float tt = fmaxf((1.0f - v + 1e-6f) * 2.0f, 0.0f);
            atomicMin(&g_colmin[bn * 256 + wn * 128 + ni * 16 + l15],
                      __float_as_uint(tt));
        }
    }

    // row-direction: fold over ni in-lane, then LDS transpose (r contiguous)
    float rmax[4][4];
    #pragma unroll
    for (int mi = 0; mi < 4; mi++)
        #pragma unroll
        for (int r = 0; r < 4; r++) {
            float v = acc[mi][0][r];
            #pragma unroll
            for (int ni = 1; ni < 8; ni++) v = fmaxf(v, acc[mi][ni][r]);
            rmax[mi][r] = v;
        }
    const int centry = wn * 16 + l15;         // 0..31
    #pragma unroll
    for (int mi = 0; mi < 4; mi++) {
        f32x4 v = {rmax[mi][0], rmax[mi][1], rmax[mi][2], rmax[mi][3]};
        *(f32x4*)&T[centry * TST + wm * 64 + mi * 16 + quad * 4] = v;
    }
    __syncthreads();

    if (tid < 128) {
        int row = tid;
        float v0 = T[row], v1 = T[TST + row];
        #pragma unroll
        for (int c = 2; c < 32; c += 2) {
            v0 = fmaxf(v0, T[c * TST + row]);
            v1 = fmaxf(v1, T[(c + 1) * TST + row]);
        }
        float v = fmaxf(v0, v1);
        float tt = fmaxf((1.0f - v + 1e-6f) * 2.0f, 0.0f);
        atomicMin(&g_rowmin[bm * 128 + row], __float_as_uint(tt));
    }
}

__global__ __launch_bounds__(1024) void finalize_t_kernel(
    const unsigned* __restrict__ rm, const unsigned* __restrict__ cm,
    const float* __restrict__ post, float* __restrict__ out)
{
    float local = 0.f;
    for (int i = threadIdx.x; i < CNT; i += 1024) {
        float t   = fminf(__uint_as_float(rm[i]), __uint_as_float(cm[i]));
        float neg = sqrtf(fmaxf(t, 0.f));
        float pos = sqrtf(fmaxf(post[i], 0.f));
        local += fmaxf(1.0f - neg + pos, 0.0f);
    }
    #pragma unroll
    for (int m = 1; m < 64; m <<= 1) local += __shfl_xor(local, m, 64);
    __shared__ float wsum[16];
    if ((threadIdx.x & 63) == 0) wsum[threadIdx.x >> 6] = local;
    __syncthreads();
    if (threadIdx.x == 0) {
        float s = 0.f;
        #pragma unroll
        for (int w = 0; w < 16; w++) s += wsum[w];
        out[0] = s * (1.0f / (float)CNT);
    }
}

// ---------------- fallback path (round-1, known passing; 96 KB ws) ----------------

#define BM 128
#define BN 128
#define BK 64
#define KST (BK + 8)

typedef __bf16 bf16x8 __attribute__((ext_vector_type(8)));

__global__ __launch_bounds__(256) void init_min_kernel(unsigned* buf, int n) {
    int i = blockIdx.x * 256 + threadIdx.x;
    if (i < n) buf[i] = 0x7F7FFFFFu;
}

__global__ __launch_bounds__(256) void dist_tile_kernel(
    const float* __restrict__ A, const float* __restrict__ P,
    unsigned* __restrict__ g_rowmin, unsigned* __restrict__ g_colmin,
    float* __restrict__ g_pos)
{
    __shared__ unsigned short As[BM * KST];
    __shared__ unsigned short Bs[BN * KST];
    __shared__ unsigned redrow[BM];
    __shared__ unsigned redcol[BN];

    const int tid  = threadIdx.x;
    const int bm   = blockIdx.y;
    const int bn   = blockIdx.x;
    const int wave = tid >> 6;
    const int lane = tid & 63;
    const int quad = lane >> 4;
    const int l15  = lane & 15;
    const int m_off = (wave >> 1) * 64;
    const int n_off = (wave & 1) * 64;

    if (tid < BM) redrow[tid] = 0x7F7FFFFFu;
    if (tid < BN) redcol[tid] = 0x7F7FFFFFu;

    f32x4 acc[4][4];
    #pragma unroll
    for (int i = 0; i < 4; i++)
        #pragma unroll
        for (int j = 0; j < 4; j++)
            acc[i][j] = (f32x4){0.f, 0.f, 0.f, 0.f};

    const int srow = tid >> 4;
    const int scol = tid & 15;

    for (int kc = 0; kc < KDIM / BK; kc++) {
        #pragma unroll
        for (int i = 0; i < 8; i++) {
            int r = srow + i * 16;
            float4 va = *(const float4*)(A + (size_t)(bm * BM + r) * KDIM + kc * BK + scol * 4);
            float4 vb = *(const float4*)(P + (size_t)(bn * BN + r) * KDIM + kc * BK + scol * 4);
            ushort4 wa, wb;
            wa.x = f2bf(va.x); wa.y = f2bf(va.y); wa.z = f2bf(va.z); wa.w = f2bf(va.w);
            wb.x = f2bf(vb.x); wb.y = f2bf(vb.y); wb.z = f2bf(vb.z); wb.w = f2bf(vb.w);
            *(ushort4*)(&As[r * KST + scol * 4]) = wa;
            *(ushort4*)(&Bs[r * KST + scol * 4]) = wb;
        }
        __syncthreads();
        #pragma unroll
        for (int ks = 0; ks < BK / 32; ks++) {
            bf16x8 af[4], bfr[4];
            #pragma unroll
            for (int mi = 0; mi < 4; mi++)
                af[mi] = *(const bf16x8*)(&As[(m_off + mi * 16 + l15) * KST + ks * 32 + quad * 8]);
            #pragma unroll
            for (int ni = 0; ni < 4; ni++)
                bfr[ni] = *(const bf16x8*)(&Bs[(n_off + ni * 16 + l15) * KST + ks * 32 + quad * 8]);
            #pragma unroll
            for (int mi = 0; mi < 4; mi++)
                #pragma unroll
                for (int ni = 0; ni < 4; ni++)
                    acc[mi][ni] = __builtin_amdgcn_mfma_f32_16x16x32_bf16(
                        af[mi], bfr[ni], acc[mi][ni], 0, 0, 0);
        }
        __syncthreads();
    }

    float rmin[4][4], cmin[4];
    #pragma unroll
    for (int mi = 0; mi < 4; mi++)
        #pragma unroll
        for (int r = 0; r < 4; r++) rmin[mi][r] = BIGF;
    #pragma unroll
    for (int ni = 0; ni < 4; ni++) cmin[ni] = BIGF;

    const int grow0 = bm * BM + m_off + quad * 4;
    const int gcol0 = bn * BN + n_off + l15;

    #pragma unroll
    for (int mi = 0; mi < 4; mi++)
        #pragma unroll
        for (int ni = 0; ni < 4; ni++) {
            int gcol = gcol0 + ni * 16;
            #pragma unroll
            for (int r = 0; r < 4; r++) {
                int grow = grow0 + mi * 16 + r;
                float s = acc[mi][ni][r];
                float d = sqrtf((1.0f - s + 1e-6f) * 2.0f);
                float dm = d;
                if (grow == gcol) { g_pos[grow] = d; dm = BIGF; }
                rmin[mi][r] = fminf(rmin[mi][r], dm);
                cmin[ni]    = fminf(cmin[ni], dm);
            }
        }

    #pragma unroll
    for (int mi = 0; mi < 4; mi++)
        #pragma unroll
        for (int r = 0; r < 4; r++) {
            float v = rmin[mi][r];
            v = fminf(v, __shfl_xor(v, 1, 64));
            v = fminf(v, __shfl_xor(v, 2, 64));
            v = fminf(v, __shfl_xor(v, 4, 64));
            v = fminf(v, __shfl_xor(v, 8, 64));
            rmin[mi][r] = v;
        }
    #pragma unroll
    for (int ni = 0; ni < 4; ni++) {
        float v = cmin[ni];
        v = fminf(v, __shfl_xor(v, 16, 64));
        v = fminf(v, __shfl_xor(v, 32, 64));
        cmin[ni] = v;
    }

    if (l15 == 0) {
        #pragma unroll
        for (int mi = 0; mi < 4; mi++)
            #pragma unroll
            for (int r = 0; r < 4; r++)
                atomicMin(&redrow[m_off + mi * 16 + quad * 4 + r],
                          __float_as_uint(rmin[mi][r]));
    }
    if (quad == 0) {
        #pragma unroll
        for (int ni = 0; ni < 4; ni++)
            atomicMin(&redcol[n_off + ni * 16 + l15], __float_as_uint(cmin[ni]));
    }
    __syncthreads();

    if (tid < 128) atomicMin(&g_rowmin[bm * BM + tid], redrow[tid]);
    else           atomicMin(&g_colmin[bn * BN + (tid - 128)], redcol[tid - 128]);
}

__global__ __launch_bounds__(1024) void finalize_kernel(
    const unsigned* __restrict__ g_rowmin, const unsigned* __restrict__ g_colmin,
    const float* __restrict__ g_pos, float* __restrict__ out)
{
    float local = 0.f;
    for (int i = threadIdx.x; i < CNT; i += 1024) {
        float neg = fminf(__uint_as_float(g_rowmin[i]), __uint_as_float(g_colmin[i]));
        float v = 1.0f - neg + g_pos[i];
        local += fmaxf(v, 0.0f);
    }
    #pragma unroll
    for (int m = 1; m < 64; m <<= 1) local += __shfl_xor(local, m, 64);
    __shared__ float wsum[16];
    if ((threadIdx.x & 63) == 0) wsum[threadIdx.x >> 6] = local;
    __syncthreads();
    if (threadIdx.x == 0) {
        float s = 0.f;
        #pragma unroll
        for (int w = 0; w < 16; w++) s += wsum[w];
        out[0] = s * (1.0f / (float)CNT);
    }
}

// ---------------- host ----------------

extern "C" void kernel_launch(void* const* d_in, const int* in_sizes, int n_in,
                              void* d_out, int out_size, void* d_ws, size_t ws_size,
                              hipStream_t stream) {
    const float* x = (const float*)d_in[0];
    float* out = (float*)d_out;

    const size_t fp8_bytes = (size_t)2 * CNT * KDIM;        // 4,194,304
    const size_t need = fp8_bytes + (size_t)2 * CNT * 4 + (size_t)CNT * 4;

    if (ws_size >= need) {
        unsigned char* xb   = (unsigned char*)d_ws;
        unsigned*      mins = (unsigned*)((char*)d_ws + fp8_bytes);
        float*         pos  = (float*)(mins + 2 * CNT);
        convert8_kernel<<<dim3(1024), dim3(256), 0, stream>>>(x, xb, mins);
        dist6_kernel<<<dim3(2048), dim3(256), 0, stream>>>(
            xb, xb + (size_t)CNT * KDIM, mins, mins + CNT, pos);
        finalize_t_kernel<<<dim3(1), dim3(1024), 0, stream>>>(mins, mins + CNT, pos, out);
    } else {
        unsigned* rowmin = (unsigned*)d_ws;
        unsigned* colmin = rowmin + CNT;
        float*    pos    = (float*)(colmin + CNT);
        init_min_kernel<<<dim3(2 * CNT / 256), dim3(256), 0, stream>>>(rowmin, 2 * CNT);
        dist_tile_kernel<<<dim3(CNT / BN, CNT / BM), dim3(256), 0, stream>>>(
            x, x + (size_t)CNT * KDIM, rowmin, colmin, pos);
        finalize_kernel<<<dim3(1), dim3(1024), 0, stream>>>(rowmin, colmin, pos, out);
    }
}

// Round 8
// 93.015 us; speedup vs baseline: 1.8225x; 1.1004x over previous
//
#include <hip/hip_runtime.h>
#include <hip/hip_fp8.h>

// HardNetLoss: a = x[:8192], p = x[8192:], d_ij = sqrt((1 - a_i·p_j + 1e-6)*2)
// pos_i = d_ii ; neg_i = min(min_{j!=i} d_ji, min_{j!=i} d_ij)
// out = mean(relu(1 - neg + pos))
//
// R7 (resubmit after infra timeout): MX-scaled fp8 MFMA (32x32x64 f8f6f4,
// unit e8m0 scales) = 2x the non-scaled fp8 rate -> MFMA pipe floor
// 16.6 -> 7.3 us. Same barrier-free direct-from-L2 K-loop as R6 (feed bytes
// unchanged). Fragment = 8 VGPRs loaded as two coalesced 1KB half-chunks
// (+0 / +1024). 32x32 C/D layout: col = lane&31,
// row = (reg&3) + 8*(reg>>2) + 4*(lane>>5)  [m74/m101; shape-determined for
// f8f6f4-scaled per m121-128]. Intra-lane byte->k order is a consistent A/B
// bijection -> cancels in the contraction; scales all 1.0 so block grouping
// is irrelevant.

#define CNT    8192
#define KDIM   256
#define BIGF   3.0e38f
#define SCALE1 0x7F7F7F7F            // 4x e8m0 bytes, each = 2^0

typedef float f32x4  __attribute__((ext_vector_type(4)));
typedef float f32x16 __attribute__((ext_vector_type(16)));
typedef int   v8i    __attribute__((ext_vector_type(8)));

union frag8 { uint4 q[2]; v8i v; };

__device__ __forceinline__ unsigned short f2bf(float f) {
    unsigned u = __float_as_uint(f);
    u += 0x7FFFu + ((u >> 16) & 1u);          // round-to-nearest-even
    return (unsigned short)(u >> 16);
}

__device__ __forceinline__ unsigned cvt4_fp8(float a, float b, float c, float d) {
#if __has_builtin(__builtin_amdgcn_cvt_pk_fp8_f32)
    unsigned v = __builtin_amdgcn_cvt_pk_fp8_f32(a, b, 0, false);
    v = __builtin_amdgcn_cvt_pk_fp8_f32(c, d, v, true);
    return v;
#else
    return (unsigned)__hip_fp8_e4m3(a).__x |
           ((unsigned)__hip_fp8_e4m3(b).__x << 8) |
           ((unsigned)__hip_fp8_e4m3(c).__x << 16) |
           ((unsigned)__hip_fp8_e4m3(d).__x << 24);
#endif
}

// ---------------- fast path ----------------

// x fp32 [16384][256] -> xb fp8, MX-fragment-packed. Chunk (rg32, kc64) is
// 2KB: half h holds j 0..15 (h=0) / 16..31 (h=1) of each lane's 32-k block;
// lane = (row%32) + 32*((col%64)/32). Thread T writes 16B at xb + T*16.
__global__ __launch_bounds__(256) void convert_mx_kernel(
    const float* __restrict__ x, unsigned char* __restrict__ xb,
    unsigned* __restrict__ mins)
{
    int T    = blockIdx.x * 256 + threadIdx.x;   // 262144 threads
    int lane = T & 63;
    int h    = (T >> 6) & 1;
    int c    = T >> 7;                           // chunk 0..2047
    int kc64 = c & 3;
    int rg   = c >> 2;                           // 32-row group
    int row  = rg * 32 + (lane & 31);
    int col0 = kc64 * 64 + (lane >> 5) * 32 + h * 16;
    const float* src = x + (size_t)row * KDIM + col0;
    float4 u0 = *(const float4*)(src);
    float4 u1 = *(const float4*)(src + 4);
    float4 u2 = *(const float4*)(src + 8);
    float4 u3 = *(const float4*)(src + 12);
    uint4 w;
    w.x = cvt4_fp8(u0.x, u0.y, u0.z, u0.w);
    w.y = cvt4_fp8(u1.x, u1.y, u1.z, u1.w);
    w.z = cvt4_fp8(u2.x, u2.y, u2.z, u2.w);
    w.w = cvt4_fp8(u3.x, u3.y, u3.z, u3.w);
    *(uint4*)(xb + (size_t)T * 16) = w;
    if (T < 2 * CNT) mins[T] = 0x7F7FFFFFu;      // FLT_MAX bits
}

// block tile 128(m) x 256(n); 4 waves 2x2; wave tile 64x128 of 32x32x64 MFMA.
#define TST 136                                   // T leading stride (f32)
__global__ __launch_bounds__(256, 2) void dist7_kernel(
    const unsigned char* __restrict__ Ab, const unsigned char* __restrict__ Pb,
    unsigned* __restrict__ g_rowmin, unsigned* __restrict__ g_colmin,
    float* __restrict__ g_pos)
{
    __shared__ float T[64 * TST];                // 34.8 KB (epilogue only)

    const int tid  = threadIdx.x;
    // XCD-aware swizzle: 8 regions of 16x16 blocks
    const int l    = blockIdx.x;
    const int xcd  = l & 7;
    const int i    = l >> 3;                     // 0..255
    const int bm   = (xcd >> 1) * 16 + (i & 15); // 0..63
    const int bn   = (xcd & 1) * 16 + (i >> 4);  // 0..31

    const int wave = tid >> 6;
    const int lane = tid & 63;
    const int l31  = lane & 31;
    const int kh   = lane >> 5;                  // k-half / C-row-half selector
    const int wm   = wave >> 1;                  // 0..1 : m half
    const int wn   = wave & 1;                   // 0..1 : n half

    f32x16 acc[2][4];
    #pragma unroll
    for (int a = 0; a < 2; a++)
        #pragma unroll
        for (int b = 0; b < 4; b++)
            #pragma unroll
            for (int r = 0; r < 16; r++)
                acc[a][b][r] = 0.f;

    // chunk (rg32, kc64) = 2KB at (rg32*4 + kc64)*2048; lane slot +lane*16,
    // halves at +0 / +1024.
    const char* Abase = (const char*)Ab + lane * 16;
    const char* Pbase = (const char*)Pb + lane * 16;
    size_t a_off[2], b_off[4];
    #pragma unroll
    for (int mi = 0; mi < 2; mi++)
        a_off[mi] = (size_t)(bm * 4 + wm * 2 + mi) << 13;    // rg32 * 8192
    #pragma unroll
    for (int ni = 0; ni < 4; ni++)
        b_off[ni] = (size_t)(bn * 8 + wn * 4 + ni) << 13;

    // K-loop: 4 steps of K=64; 12 coalesced dwordx4 + 8 MFMA per step.
    #pragma unroll
    for (int kc = 0; kc < 4; kc++) {
        frag8 af[2], bf[4];
        #pragma unroll
        for (int mi = 0; mi < 2; mi++) {
            af[mi].q[0] = *(const uint4*)(Abase + a_off[mi] + kc * 2048);
            af[mi].q[1] = *(const uint4*)(Abase + a_off[mi] + kc * 2048 + 1024);
        }
        #pragma unroll
        for (int ni = 0; ni < 4; ni++) {
            bf[ni].q[0] = *(const uint4*)(Pbase + b_off[ni] + kc * 2048);
            bf[ni].q[1] = *(const uint4*)(Pbase + b_off[ni] + kc * 2048 + 1024);
        }
        #pragma unroll
        for (int mi = 0; mi < 2; mi++)
            #pragma unroll
            for (int ni = 0; ni < 4; ni++)
                acc[mi][ni] = __builtin_amdgcn_mfma_scale_f32_32x32x64_f8f6f4(
                    af[mi].v, bf[ni].v, acc[mi][ni],
                    0, 0,                 // cbsz = fp8 e4m3, blgp = fp8 e4m3
                    0, SCALE1,            // scale_a opsel, scale_a
                    0, SCALE1);           // scale_b opsel, scale_b
    }

    // ---- epilogue. C/D: col = l31, row = (reg&3) + 8*(reg>>2) + 4*kh.
    // local row rl = wm*64 + mi*32 + rowf(reg)   (0..127)
    // local col cl = wn*128 + ni*32 + l31        (0..255)

    if ((bm >> 1) == bn) {                       // diagonal band
        const int dstart = (bm & 1) * 128;
        #pragma unroll
        for (int mi = 0; mi < 2; mi++)
            #pragma unroll
            for (int ni = 0; ni < 4; ni++)
                #pragma unroll
                for (int reg = 0; reg < 16; reg++) {
                    int rl = wm * 64 + mi * 32 + (reg & 3) + 8 * (reg >> 2) + 4 * kh;
                    int cl = wn * 128 + ni * 32 + l31;
                    if (cl == rl + dstart) {
                        g_pos[bm * 128 + rl] = (1.0f - acc[mi][ni][reg] + 1e-6f) * 2.0f;
                        acc[mi][ni][reg] = -BIGF;
                    }
                }
    }

    // col-direction (min over rows => max s): in-lane fold + 1 shuffle (kh)
    #pragma unroll
    for (int ni = 0; ni < 4; ni++) {
        float v = -BIGF;
        #pragma unroll
        for (int mi = 0; mi < 2; mi++)
            #pragma unroll
            for (int reg = 0; reg < 16; reg++)
                v = fmaxf(v, acc[mi][ni][reg]);
        v = fmaxf(v, __shfl_xor(v, 32, 64));
        if (kh == 0) {
            float tt = fmaxf((1.0f - v + 1e-6f) * 2.0f, 0.0f);
            atomicMin(&g_colmin[bn * 256 + wn * 128 + ni * 32 + l31],
                      __float_as_uint(tt));
        }
    }

    // row-direction: fold over ni in-lane; rows come in reg&3-contiguous runs
    // of 4 -> f32x4 LDS transpose writes; waves write disjoint (entry,row).
    const int entry = wn * 32 + l31;             // 0..63
    #pragma unroll
    for (int mi = 0; mi < 2; mi++)
        #pragma unroll
        for (int q = 0; q < 4; q++) {
            f32x4 v;
            #pragma unroll
            for (int rr = 0; rr < 4; rr++) {
                float m = acc[mi][0][q * 4 + rr];
                #pragma unroll
                for (int ni = 1; ni < 4; ni++)
                    m = fmaxf(m, acc[mi][ni][q * 4 + rr]);
                v[rr] = m;
            }
            *(f32x4*)&T[entry * TST + wm * 64 + mi * 32 + q * 8 + kh * 4] = v;
        }
    __syncthreads();

    if (tid < 128) {
        int row = tid;
        float v0 = T[row], v1 = T[TST + row];
        #pragma unroll
        for (int e = 2; e < 64; e += 2) {
            v0 = fmaxf(v0, T[e * TST + row]);
            v1 = fmaxf(v1, T[(e + 1) * TST + row]);
        }
        float v = fmaxf(v0, v1);
        float tt = fmaxf((1.0f - v + 1e-6f) * 2.0f, 0.0f);
        atomicMin(&g_rowmin[bm * 128 + row], __float_as_uint(tt));
    }
}

__global__ __launch_bounds__(1024) void finalize_t_kernel(
    const unsigned* __restrict__ rm, const unsigned* __restrict__ cm,
    const float* __restrict__ post, float* __restrict__ out)
{
    float local = 0.f;
    for (int i = threadIdx.x; i < CNT; i += 1024) {
        float t   = fminf(__uint_as_float(rm[i]), __uint_as_float(cm[i]));
        float neg = sqrtf(fmaxf(t, 0.f));
        float pos = sqrtf(fmaxf(post[i], 0.f));
        local += fmaxf(1.0f - neg + pos, 0.0f);
    }
    #pragma unroll
    for (int m = 1; m < 64; m <<= 1) local += __shfl_xor(local, m, 64);
    __shared__ float wsum[16];
    if ((threadIdx.x & 63) == 0) wsum[threadIdx.x >> 6] = local;
    __syncthreads();
    if (threadIdx.x == 0) {
        float s = 0.f;
        #pragma unroll
        for (int w = 0; w < 16; w++) s += wsum[w];
        out[0] = s * (1.0f / (float)CNT);
    }
}

// ---------------- fallback path (round-1, known passing; 96 KB ws) ----------------

#define BM 128
#define BN 128
#define BK 64
#define KST (BK + 8)

typedef __bf16 bf16x8 __attribute__((ext_vector_type(8)));

__global__ __launch_bounds__(256) void init_min_kernel(unsigned* buf, int n) {
    int i = blockIdx.x * 256 + threadIdx.x;
    if (i < n) buf[i] = 0x7F7FFFFFu;
}

__global__ __launch_bounds__(256) void dist_tile_kernel(
    const float* __restrict__ A, const float* __restrict__ P,
    unsigned* __restrict__ g_rowmin, unsigned* __restrict__ g_colmin,
    float* __restrict__ g_pos)
{
    __shared__ unsigned short As[BM * KST];
    __shared__ unsigned short Bs[BN * KST];
    __shared__ unsigned redrow[BM];
    __shared__ unsigned redcol[BN];

    const int tid  = threadIdx.x;
    const int bm   = blockIdx.y;
    const int bn   = blockIdx.x;
    const int wave = tid >> 6;
    const int lane = tid & 63;
    const int quad = lane >> 4;
    const int l15  = lane & 15;
    const int m_off = (wave >> 1) * 64;
    const int n_off = (wave & 1) * 64;

    if (tid < BM) redrow[tid] = 0x7F7FFFFFu;
    if (tid < BN) redcol[tid] = 0x7F7FFFFFu;

    f32x4 acc[4][4];
    #pragma unroll
    for (int i = 0; i < 4; i++)
        #pragma unroll
        for (int j = 0; j < 4; j++)
            acc[i][j] = (f32x4){0.f, 0.f, 0.f, 0.f};

    const int srow = tid >> 4;
    const int scol = tid & 15;

    for (int kc = 0; kc < KDIM / BK; kc++) {
        #pragma unroll
        for (int i = 0; i < 8; i++) {
            int r = srow + i * 16;
            float4 va = *(const float4*)(A + (size_t)(bm * BM + r) * KDIM + kc * BK + scol * 4);
            float4 vb = *(const float4*)(P + (size_t)(bn * BN + r) * KDIM + kc * BK + scol * 4);
            ushort4 wa, wb;
            wa.x = f2bf(va.x); wa.y = f2bf(va.y); wa.z = f2bf(va.z); wa.w = f2bf(va.w);
            wb.x = f2bf(vb.x); wb.y = f2bf(vb.y); wb.z = f2bf(vb.z); wb.w = f2bf(vb.w);
            *(ushort4*)(&As[r * KST + scol * 4]) = wa;
            *(ushort4*)(&Bs[r * KST + scol * 4]) = wb;
        }
        __syncthreads();
        #pragma unroll
        for (int ks = 0; ks < BK / 32; ks++) {
            bf16x8 af[4], bfr[4];
            #pragma unroll
            for (int mi = 0; mi < 4; mi++)
                af[mi] = *(const bf16x8*)(&As[(m_off + mi * 16 + l15) * KST + ks * 32 + quad * 8]);
            #pragma unroll
            for (int ni = 0; ni < 4; ni++)
                bfr[ni] = *(const bf16x8*)(&Bs[(n_off + ni * 16 + l15) * KST + ks * 32 + quad * 8]);
            #pragma unroll
            for (int mi = 0; mi < 4; mi++)
                #pragma unroll
                for (int ni = 0; ni < 4; ni++)
                    acc[mi][ni] = __builtin_amdgcn_mfma_f32_16x16x32_bf16(
                        af[mi], bfr[ni], acc[mi][ni], 0, 0, 0);
        }
        __syncthreads();
    }

    float rmin[4][4], cmin[4];
    #pragma unroll
    for (int mi = 0; mi < 4; mi++)
        #pragma unroll
        for (int r = 0; r < 4; r++) rmin[mi][r] = BIGF;
    #pragma unroll
    for (int ni = 0; ni < 4; ni++) cmin[ni] = BIGF;

    const int grow0 = bm * BM + m_off + quad * 4;
    const int gcol0 = bn * BN + n_off + l15;

    #pragma unroll
    for (int mi = 0; mi < 4; mi++)
        #pragma unroll
        for (int ni = 0; ni < 4; ni++) {
            int gcol = gcol0 + ni * 16;
            #pragma unroll
            for (int r = 0; r < 4; r++) {
                int grow = grow0 + mi * 16 + r;
                float s = acc[mi][ni][r];
                float d = sqrtf((1.0f - s + 1e-6f) * 2.0f);
                float dm = d;
                if (grow == gcol) { g_pos[grow] = d; dm = BIGF; }
                rmin[mi][r] = fminf(rmin[mi][r], dm);
                cmin[ni]    = fminf(cmin[ni], dm);
            }
        }

    #pragma unroll
    for (int mi = 0; mi < 4; mi++)
        #pragma unroll
        for (int r = 0; r < 4; r++) {
            float v = rmin[mi][r];
            v = fminf(v, __shfl_xor(v, 1, 64));
            v = fminf(v, __shfl_xor(v, 2, 64));
            v = fminf(v, __shfl_xor(v, 4, 64));
            v = fminf(v, __shfl_xor(v, 8, 64));
            rmin[mi][r] = v;
        }
    #pragma unroll
    for (int ni = 0; ni < 4; ni++) {
        float v = cmin[ni];
        v = fminf(v, __shfl_xor(v, 16, 64));
        v = fminf(v, __shfl_xor(v, 32, 64));
        cmin[ni] = v;
    }

    if (l15 == 0) {
        #pragma unroll
        for (int mi = 0; mi < 4; mi++)
            #pragma unroll
            for (int r = 0; r < 4; r++)
                atomicMin(&redrow[m_off + mi * 16 + quad * 4 + r],
                          __float_as_uint(rmin[mi][r]));
    }
    if (quad == 0) {
        #pragma unroll
        for (int ni = 0; ni < 4; ni++)
            atomicMin(&redcol[n_off + ni * 16 + l15], __float_as_uint(cmin[ni]));
    }
    __syncthreads();

    if (tid < 128) atomicMin(&g_rowmin[bm * BM + tid], redrow[tid]);
    else           atomicMin(&g_colmin[bn * BN + (tid - 128)], redcol[tid - 128]);
}

__global__ __launch_bounds__(1024) void finalize_kernel(
    const unsigned* __restrict__ g_rowmin, const unsigned* __restrict__ g_colmin,
    const float* __restrict__ g_pos, float* __restrict__ out)
{
    float local = 0.f;
    for (int i = threadIdx.x; i < CNT; i += 1024) {
        float neg = fminf(__uint_as_float(g_rowmin[i]), __uint_as_float(g_colmin[i]));
        float v = 1.0f - neg + g_pos[i];
        local += fmaxf(v, 0.0f);
    }
    #pragma unroll
    for (int m = 1; m < 64; m <<= 1) local += __shfl_xor(local, m, 64);
    __shared__ float wsum[16];
    if ((threadIdx.x & 63) == 0) wsum[threadIdx.x >> 6] = local;
    __syncthreads();
    if (threadIdx.x == 0) {
        float s = 0.f;
        #pragma unroll
        for (int w = 0; w < 16; w++) s += wsum[w];
        out[0] = s * (1.0f / (float)CNT);
    }
}

// ---------------- host ----------------

extern "C" void kernel_launch(void* const* d_in, const int* in_sizes, int n_in,
                              void* d_out, int out_size, void* d_ws, size_t ws_size,
                              hipStream_t stream) {
    const float* x = (const float*)d_in[0];
    float* out = (float*)d_out;

    const size_t fp8_bytes = (size_t)2 * CNT * KDIM;        // 4,194,304
    const size_t need = fp8_bytes + (size_t)2 * CNT * 4 + (size_t)CNT * 4;

    if (ws_size >= need) {
        unsigned char* xb   = (unsigned char*)d_ws;
        unsigned*      mins = (unsigned*)((char*)d_ws + fp8_bytes);
        float*         pos  = (float*)(mins + 2 * CNT);
        convert_mx_kernel<<<dim3(1024), dim3(256), 0, stream>>>(x, xb, mins);
        dist7_kernel<<<dim3(2048), dim3(256), 0, stream>>>(
            xb, xb + (size_t)CNT * KDIM, mins, mins + CNT, pos);
        finalize_t_kernel<<<dim3(1), dim3(1024), 0, stream>>>(mins, mins + CNT, pos, out);
    } else {
        unsigned* rowmin = (unsigned*)d_ws;
        unsigned* colmin = rowmin + CNT;
        float*    pos    = (float*)(colmin + CNT);
        init_min_kernel<<<dim3(2 * CNT / 256), dim3(256), 0, stream>>>(rowmin, 2 * CNT);
        dist_tile_kernel<<<dim3(CNT / BN, CNT / BM), dim3(256), 0, stream>>>(
            x, x + (size_t)CNT * KDIM, rowmin, colmin, pos);
        finalize_kernel<<<dim3(1), dim3(1024), 0, stream>>>(rowmin, colmin, pos, out);
    }
}